// Round 7
// baseline (584.960 us; speedup 1.0000x reference)
//
#include <hip/hip_runtime.h>
#include <math.h>

#define DEVI __device__ __forceinline__

typedef unsigned int u32;
typedef unsigned short u16;
typedef __attribute__((ext_vector_type(8))) __bf16 bf16x8;
typedef __attribute__((ext_vector_type(8))) u16 u16x8;
typedef __attribute__((ext_vector_type(4))) float f32x4;

DEVI float silu_f(float x) { return x * (1.0f / (1.0f + __expf(-x))); }
DEVI float softplus_f(float x) {
  return x > 0.0f ? x + log1pf(__expf(-x)) : log1pf(__expf(x));
}

DEVI u32 bf16_rne(float f) {
  u32 u = __float_as_uint(f);
  return (u + 0x7fffu + ((u >> 16) & 1u)) >> 16;
}
// packed split: high 16 bits = bf16(f), low 16 bits = bf16(f - hi)
DEVI u32 pack_hl(float f) {
  u32 h = bf16_rne(f);
  float hf = __uint_as_float(h << 16);
  u32 l = bf16_rne(f - hf);
  return (h << 16) | l;
}

DEVI void load16(float* r, const float* __restrict__ p) {
  const float4* q = (const float4*)p;
  float4 a = q[0], b = q[1], c = q[2], d = q[3];
  r[0]=a.x; r[1]=a.y; r[2]=a.z; r[3]=a.w;
  r[4]=b.x; r[5]=b.y; r[6]=b.z; r[7]=b.w;
  r[8]=c.x; r[9]=c.y; r[10]=c.z; r[11]=c.w;
  r[12]=d.x; r[13]=d.y; r[14]=d.z; r[15]=d.w;
}
DEVI void store16(float* __restrict__ p, const float* r) {
  float4* q = (float4*)p;
  q[0] = make_float4(r[0],r[1],r[2],r[3]);
  q[1] = make_float4(r[4],r[5],r[6],r[7]);
  q[2] = make_float4(r[8],r[9],r[10],r[11]);
  q[3] = make_float4(r[12],r[13],r[14],r[15]);
}

// unpack 8 packed u32 (from two uint4 LDS reads) into hi/lo bf16x8 fragments
DEVI void unpack_hl(uint4 p0, uint4 p1, bf16x8* h, bf16x8* l) {
  u32 a[8] = {p0.x, p0.y, p0.z, p0.w, p1.x, p1.y, p1.z, p1.w};
  u16x8 hh, ll;
  #pragma unroll
  for (int i = 0; i < 8; ++i) { hh[i] = (u16)(a[i] >> 16); ll[i] = (u16)a[i]; }
  *h = *(bf16x8*)&hh;
  *l = *(bf16x8*)&ll;
}

// ---------------------------------------------------------------------------
// Weight prep: convert 5 fp32 weight matrices to packed hi/lo bf16 (u32).
// ---------------------------------------------------------------------------
constexpr int WOFF1 = 0, WOFFO1 = 32768, WOFFL = 49152, WOFF2 = 81920, WOFFO2 = 212992;
constexpr int WTOT = 278528;

__global__ __launch_bounds__(256) void wprep_kernel(
    const float* __restrict__ w1, const float* __restrict__ wo1,
    const float* __restrict__ wl, const float* __restrict__ w2,
    const float* __restrict__ wo2, u32* __restrict__ dst)
{
  int i = blockIdx.x * 256 + threadIdx.x;
  float v;
  if (i < WOFFO1)       v = w1[i];
  else if (i < WOFFL)   v = wo1[i - WOFFO1];
  else if (i < WOFF2)   v = wl[i - WOFFL];
  else if (i < WOFFO2)  v = w2[i - WOFF2];
  else                  v = wo2[i - WOFFO2];
  dst[i] = pack_hl(v);
}

// ---------------------------------------------------------------------------
// Transpose: fp32 (b, C, L) -> packed u32 (b*L, C)
// ---------------------------------------------------------------------------
__global__ __launch_bounds__(256) void tpose_kernel(
    const float* __restrict__ in, u32* __restrict__ out, int C, int L)
{
  __shared__ float t[32][33];
  const int l0 = blockIdx.x * 32, c0 = blockIdx.y * 32, b = blockIdx.z;
  const int tx = threadIdx.x & 31, ty = threadIdx.x >> 5;
  const float* src = in + ((long)b * C + c0) * L + l0;
  #pragma unroll
  for (int r = 0; r < 32; r += 8) t[ty + r][tx] = src[(long)(ty + r) * L + tx];
  __syncthreads();
  u32* dst = out + ((long)b * L + l0) * C + c0;
  #pragma unroll
  for (int r = 0; r < 32; r += 8) dst[(long)(ty + r) * C + tx] = pack_hl(t[tx][ty + r]);
}

// ---------------------------------------------------------------------------
// MFMA GEMM (bf16x3 split), software-pipelined: global loads for iter k+1 are
// issued before the MFMA section of iter k (vmcnt waits land at the next
// ds_write, after MFMA). Chunk-major packed uint4 LDS tiles (bank-balanced).
// Block 128x128, 4 waves (2x2), wave tile 64x64.
// EPI 0: split + transposed fp32 write (xz -> xcpre_t/z_t, (b,di,L))
// EPI 1: silu, packed u32 row-major write
// ---------------------------------------------------------------------------
template<int EPI>
__global__ __launch_bounds__(256) void mgemm_kernel(
    const u32* __restrict__ Ap, const u32* __restrict__ Wp,
    const float* __restrict__ bias, int M, int N, int K,
    float* __restrict__ out0, float* __restrict__ out1,
    u32* __restrict__ outp, int di, int L)
{
  __shared__ uint4 Asm[8][128];   // 16 KB
  __shared__ uint4 Bsm[8][128];   // 16 KB
  const int tid = threadIdx.x;
  const int wid = tid >> 6, lane = tid & 63;
  const int lm = lane & 15, lq = lane >> 4;
  const int m0 = blockIdx.y * 128, n0 = blockIdx.x * 128;
  const int wr = (wid >> 1) * 64, wn = (wid & 1) * 64;
  const int sr = tid >> 1;            // staging row 0..127
  const int sh = (tid & 1) * 4;       // staging hc base (0 or 4)

  f32x4 acc[4][4];
  #pragma unroll
  for (int i = 0; i < 4; ++i)
    #pragma unroll
    for (int j = 0; j < 4; ++j)
      #pragma unroll
      for (int r = 0; r < 4; ++r) acc[i][j][r] = 0.0f;

  const u32* ga = Ap + (long)(m0 + sr) * K + sh * 4;
  const u32* gb = Wp + (long)(n0 + sr) * K + sh * 4;

  uint4 av[4], bv[4];
  #pragma unroll
  for (int q = 0; q < 4; ++q) av[q] = *(const uint4*)(ga + 4 * q);
  #pragma unroll
  for (int q = 0; q < 4; ++q) bv[q] = *(const uint4*)(gb + 4 * q);

  for (int k0 = 0; k0 < K; k0 += 32) {
    #pragma unroll
    for (int q = 0; q < 4; ++q) Asm[sh + q][sr] = av[q];
    #pragma unroll
    for (int q = 0; q < 4; ++q) Bsm[sh + q][sr] = bv[q];
    __syncthreads();

    if (k0 + 32 < K) {
      #pragma unroll
      for (int q = 0; q < 4; ++q) av[q] = *(const uint4*)(ga + k0 + 32 + 4 * q);
      #pragma unroll
      for (int q = 0; q < 4; ++q) bv[q] = *(const uint4*)(gb + k0 + 32 + 4 * q);
    }

    bf16x8 fah[4], fal[4];
    #pragma unroll
    for (int i = 0; i < 4; ++i) {
      uint4 p0 = Asm[2 * lq][wr + 16 * i + lm];
      uint4 p1 = Asm[2 * lq + 1][wr + 16 * i + lm];
      unpack_hl(p0, p1, &fah[i], &fal[i]);
    }
    #pragma unroll
    for (int j = 0; j < 4; ++j) {
      uint4 p0 = Bsm[2 * lq][wn + 16 * j + lm];
      uint4 p1 = Bsm[2 * lq + 1][wn + 16 * j + lm];
      bf16x8 fbh, fbl;
      unpack_hl(p0, p1, &fbh, &fbl);
      #pragma unroll
      for (int i = 0; i < 4; ++i) {
        acc[i][j] = __builtin_amdgcn_mfma_f32_16x16x32_bf16(fah[i], fbh, acc[i][j], 0, 0, 0);
        acc[i][j] = __builtin_amdgcn_mfma_f32_16x16x32_bf16(fah[i], fbl, acc[i][j], 0, 0, 0);
        acc[i][j] = __builtin_amdgcn_mfma_f32_16x16x32_bf16(fal[i], fbh, acc[i][j], 0, 0, 0);
      }
    }
    __syncthreads();
  }

  if constexpr (EPI == 0) {
    const int b = m0 >> 12;
    const int lb = (m0 & 4095) + wr;
    #pragma unroll
    for (int j = 0; j < 4; ++j) {
      const int n = n0 + wn + 16 * j + lm;
      const float bv2 = bias[n];
      float* base = (n < di) ? out0 + ((long)b * di + n) * L
                             : out1 + ((long)b * di + (n - di)) * L;
      #pragma unroll
      for (int i = 0; i < 4; ++i) {
        const int l = lb + 16 * i + lq * 4;
        *(float4*)(base + l) = make_float4(acc[i][j][0] + bv2, acc[i][j][1] + bv2,
                                           acc[i][j][2] + bv2, acc[i][j][3] + bv2);
      }
    }
  } else {
    #pragma unroll
    for (int j = 0; j < 4; ++j) {
      const int n = n0 + wn + 16 * j + lm;
      const float bv2 = bias[n];
      #pragma unroll
      for (int i = 0; i < 4; ++i) {
        const long mg = m0 + wr + 16 * i + lq * 4;
        #pragma unroll
        for (int r = 0; r < 4; ++r)
          outp[(mg + r) * N + n] = pack_hl(silu_f(acc[i][j][r] + bv2));
      }
    }
  }
}

// ---------------------------------------------------------------------------
// MFMA GEMM + fused LayerNorm over full width BN, software-pipelined like
// mgemm. Block 64xBN, 4 waves split along N, wave tile 64x(BN/4).
// EPI 2: packed u32 row-major write.  EPI 3: fp32 transposed write (b,BN,L).
// ---------------------------------------------------------------------------
template<int BN, int EPI>
__global__ __launch_bounds__(256) void lgemm_kernel(
    const u32* __restrict__ Ap, const u32* __restrict__ Wp,
    const float* __restrict__ lnw, const float* __restrict__ lnb,
    int M, int K, u32* __restrict__ outp, float* __restrict__ outf, int L)
{
  constexpr int NT = BN / 64;
  __shared__ uint4 Asm[8][64];     // 8 KB
  __shared__ uint4 Bsm[8][BN];     // 16/32 KB
  __shared__ float red[4][64];
  __shared__ float muS[64], rsS[64];

  const int tid = threadIdx.x;
  const int wid = tid >> 6, lane = tid & 63;
  const int lm = lane & 15, lq = lane >> 4;
  const int m0 = blockIdx.x * 64;
  const int wn = wid * (BN / 4);
  const int sa_r = tid >> 2;           // 0..63
  const int sa_h = (tid & 3) * 2;      // hc base 0,2,4,6

  f32x4 acc[4][NT];
  #pragma unroll
  for (int i = 0; i < 4; ++i)
    #pragma unroll
    for (int j = 0; j < NT; ++j)
      #pragma unroll
      for (int r = 0; r < 4; ++r) acc[i][j][r] = 0.0f;

  const u32* ga = Ap + (long)(m0 + sa_r) * K + sa_h * 4;

  uint4 pa[2], pb[2][NT];
  pa[0] = *(const uint4*)ga;
  pa[1] = *(const uint4*)(ga + 4);
  #pragma unroll
  for (int it = 0; it < NT; ++it) {
    const int idx = tid + it * 256;
    const int n = idx >> 2, c = (idx & 3) * 2;
    const u32* gw = Wp + (long)n * K + c * 4;
    pb[0][it] = *(const uint4*)gw;
    pb[1][it] = *(const uint4*)(gw + 4);
  }

  for (int k0 = 0; k0 < K; k0 += 32) {
    Asm[sa_h][sa_r] = pa[0];
    Asm[sa_h + 1][sa_r] = pa[1];
    #pragma unroll
    for (int it = 0; it < NT; ++it) {
      const int idx = tid + it * 256;
      const int n = idx >> 2, c = (idx & 3) * 2;
      Bsm[c][n] = pb[0][it];
      Bsm[c + 1][n] = pb[1][it];
    }
    __syncthreads();

    if (k0 + 32 < K) {
      pa[0] = *(const uint4*)(ga + k0 + 32);
      pa[1] = *(const uint4*)(ga + k0 + 36);
      #pragma unroll
      for (int it = 0; it < NT; ++it) {
        const int idx = tid + it * 256;
        const int n = idx >> 2, c = (idx & 3) * 2;
        const u32* gw = Wp + (long)n * K + k0 + 32 + c * 4;
        pb[0][it] = *(const uint4*)gw;
        pb[1][it] = *(const uint4*)(gw + 4);
      }
    }

    bf16x8 fah[4], fal[4];
    #pragma unroll
    for (int i = 0; i < 4; ++i) {
      uint4 p0 = Asm[2 * lq][16 * i + lm];
      uint4 p1 = Asm[2 * lq + 1][16 * i + lm];
      unpack_hl(p0, p1, &fah[i], &fal[i]);
    }
    #pragma unroll
    for (int j = 0; j < NT; ++j) {
      uint4 p0 = Bsm[2 * lq][wn + 16 * j + lm];
      uint4 p1 = Bsm[2 * lq + 1][wn + 16 * j + lm];
      bf16x8 fbh, fbl;
      unpack_hl(p0, p1, &fbh, &fbl);
      #pragma unroll
      for (int i = 0; i < 4; ++i) {
        acc[i][j] = __builtin_amdgcn_mfma_f32_16x16x32_bf16(fah[i], fbh, acc[i][j], 0, 0, 0);
        acc[i][j] = __builtin_amdgcn_mfma_f32_16x16x32_bf16(fah[i], fbl, acc[i][j], 0, 0, 0);
        acc[i][j] = __builtin_amdgcn_mfma_f32_16x16x32_bf16(fal[i], fbh, acc[i][j], 0, 0, 0);
      }
    }
    __syncthreads();
  }

  // ---- fused LayerNorm over BN ----
  float part[4][4];
  #pragma unroll
  for (int i = 0; i < 4; ++i)
    #pragma unroll
    for (int r = 0; r < 4; ++r) {
      float s = 0.0f;
      #pragma unroll
      for (int j = 0; j < NT; ++j) s += acc[i][j][r];
      part[i][r] = s;
    }
  #pragma unroll
  for (int off = 1; off < 16; off <<= 1)
    #pragma unroll
    for (int i = 0; i < 4; ++i)
      #pragma unroll
      for (int r = 0; r < 4; ++r) part[i][r] += __shfl_xor(part[i][r], off);
  if (lm == 0) {
    #pragma unroll
    for (int i = 0; i < 4; ++i)
      #pragma unroll
      for (int r = 0; r < 4; ++r) red[wid][16 * i + 4 * lq + r] = part[i][r];
  }
  __syncthreads();
  if (tid < 64)
    muS[tid] = (red[0][tid] + red[1][tid] + red[2][tid] + red[3][tid]) * (1.0f / BN);
  __syncthreads();
  float mu_l[4][4];
  #pragma unroll
  for (int i = 0; i < 4; ++i)
    #pragma unroll
    for (int r = 0; r < 4; ++r) mu_l[i][r] = muS[16 * i + 4 * lq + r];
  #pragma unroll
  for (int i = 0; i < 4; ++i)
    #pragma unroll
    for (int r = 0; r < 4; ++r) {
      float s = 0.0f;
      #pragma unroll
      for (int j = 0; j < NT; ++j) {
        float d = acc[i][j][r] - mu_l[i][r];
        s = fmaf(d, d, s);
      }
      part[i][r] = s;
    }
  #pragma unroll
  for (int off = 1; off < 16; off <<= 1)
    #pragma unroll
    for (int i = 0; i < 4; ++i)
      #pragma unroll
      for (int r = 0; r < 4; ++r) part[i][r] += __shfl_xor(part[i][r], off);
  if (lm == 0) {
    #pragma unroll
    for (int i = 0; i < 4; ++i)
      #pragma unroll
      for (int r = 0; r < 4; ++r) red[wid][16 * i + 4 * lq + r] = part[i][r];
  }
  __syncthreads();
  if (tid < 64)
    rsS[tid] = rsqrtf((red[0][tid] + red[1][tid] + red[2][tid] + red[3][tid]) * (1.0f / BN)
                      + 1e-5f);
  __syncthreads();
  float rs_l[4][4];
  #pragma unroll
  for (int i = 0; i < 4; ++i)
    #pragma unroll
    for (int r = 0; r < 4; ++r) rs_l[i][r] = rsS[16 * i + 4 * lq + r];

  if constexpr (EPI == 2) {
    #pragma unroll
    for (int j = 0; j < NT; ++j) {
      const int n = wn + 16 * j + lm;
      const float g = lnw[n], bb = lnb[n];
      #pragma unroll
      for (int i = 0; i < 4; ++i) {
        #pragma unroll
        for (int r = 0; r < 4; ++r) {
          const long mg = m0 + 16 * i + 4 * lq + r;
          outp[mg * BN + n] =
              pack_hl((acc[i][j][r] - mu_l[i][r]) * rs_l[i][r] * g + bb);
        }
      }
    }
  } else {
    const int b = m0 >> 12;
    const int lb = m0 & 4095;
    #pragma unroll
    for (int j = 0; j < NT; ++j) {
      const int n = wn + 16 * j + lm;
      const float g = lnw[n], bb = lnb[n];
      #pragma unroll
      for (int i = 0; i < 4; ++i) {
        const int l = lb + 16 * i + 4 * lq;
        float4 v;
        v.x = (acc[i][j][0] - mu_l[i][0]) * rs_l[i][0] * g + bb;
        v.y = (acc[i][j][1] - mu_l[i][1]) * rs_l[i][1] * g + bb;
        v.z = (acc[i][j][2] - mu_l[i][2]) * rs_l[i][2] * g + bb;
        v.w = (acc[i][j][3] - mu_l[i][3]) * rs_l[i][3] * g + bb;
        *(float4*)(outf + ((long)b * BN + n) * L + l) = v;
      }
    }
  }
}

// ---------------------------------------------------------------------------
// Fused conv + x-proj + dt: block = 64 positions x all DI channels.
// Per wave: DI/4 channels, lane = position. Conv neighbors via __shfl_up,
// per-lane xds accumulators, LDS cross-wave reduce; dt/softplus + B/C inline.
// grid (L/64, B). Saves the xc re-read and the partial-scratch round-trip.
// ---------------------------------------------------------------------------
template<int DI, int R>
__global__ __launch_bounds__(256) void cxp_kernel(
    const float* __restrict__ xcpre_t, const float* __restrict__ cw,
    const float* __restrict__ cb, const float* __restrict__ wx,
    const float* __restrict__ wdt, const float* __restrict__ bdt,
    float* __restrict__ xc_t, float* __restrict__ dt_t,
    float* __restrict__ bc_t, int L)
{
  constexpr int NP = R + 4;
  constexpr int CPW = DI / 4;          // channels per wave
  __shared__ float s_w[DI * NP];       // phase A: wx^T [ch][j]; then wdt/bdt
  __shared__ float s_p[4 * NP * 64];   // per-wave partials -> xds

  const int tid = threadIdx.x;
  const int w = tid >> 6, lane = tid & 63;
  const int l0 = blockIdx.x * 64;
  const int b = blockIdx.y;
  const int ch0 = w * CPW;

  for (int idx = tid; idx < NP * DI; idx += 256) {
    const int j = idx / DI, ch = idx - j * DI;
    s_w[ch * NP + j] = wx[idx];
  }
  __syncthreads();

  // ---- phase A: conv+silu -> xc (global) + partial xds in registers ----
  float acc[NP];
  #pragma unroll
  for (int j = 0; j < NP; ++j) acc[j] = 0.0f;
  const long rowb0 = ((long)b * DI + ch0) * L + l0;
  #pragma unroll 4
  for (int c = 0; c < CPW; ++c) {
    const int ch = ch0 + c;
    const float* __restrict__ row = xcpre_t + rowb0 + (long)c * L;
    const float v = row[lane];
    float v1 = __shfl_up(v, 1);
    float v2 = __shfl_up(v, 2);
    float v3 = __shfl_up(v, 3);
    if (lane < 3) {
      if (l0 > 0) {
        if (lane == 0)      { v1 = row[-1]; v2 = row[-2]; v3 = row[-3]; }
        else if (lane == 1) { v2 = row[-1]; v3 = row[-2]; }
        else                { v3 = row[-1]; }
      } else {
        if (lane == 0)      { v1 = 0.0f; v2 = 0.0f; v3 = 0.0f; }
        else if (lane == 1) { v2 = 0.0f; v3 = 0.0f; }
        else                { v3 = 0.0f; }
      }
    }
    const float4 cwv = *(const float4*)(cw + ch * 4);
    float s = cb[ch];
    s = fmaf(v3, cwv.x, s);
    s = fmaf(v2, cwv.y, s);
    s = fmaf(v1, cwv.z, s);
    s = fmaf(v,  cwv.w, s);
    const float xc = silu_f(s);
    xc_t[rowb0 + (long)c * L + lane] = xc;
    const float* wr = &s_w[ch * NP];
    #pragma unroll
    for (int j = 0; j < NP; ++j) acc[j] = fmaf(xc, wr[j], acc[j]);
  }
  #pragma unroll
  for (int j = 0; j < NP; ++j) s_p[(w * NP + j) * 64 + lane] = acc[j];
  __syncthreads();

  // ---- reduce partials; overlay wdt/bdt into s_w; B/C out ----
  float* s_wd = s_w;            // [DI][R]
  float* s_bd = s_w + DI * R;   // [DI]
  for (int idx = tid; idx < DI * R; idx += 256) s_wd[idx] = wdt[idx];
  for (int idx = tid; idx < DI; idx += 256) s_bd[idx] = bdt[idx];
  for (int idx = tid; idx < NP * 64; idx += 256) {
    const int j = idx >> 6, pos = idx & 63;
    float s = s_p[(0 * NP + j) * 64 + pos] + s_p[(1 * NP + j) * 64 + pos]
            + s_p[(2 * NP + j) * 64 + pos] + s_p[(3 * NP + j) * 64 + pos];
    if (j < R) s_p[j * 64 + pos] = s;
    else       bc_t[((long)b * 4 + (j - R)) * L + l0 + pos] = s;
  }
  __syncthreads();

  // ---- phase B: dt over this wave's channel slice ----
  float xr[R];
  #pragma unroll
  for (int j = 0; j < R; ++j) xr[j] = s_p[j * 64 + lane];
  float* __restrict__ dtb = dt_t + ((long)b * DI + ch0) * L + l0 + lane;
  #pragma unroll 4
  for (int c = 0; c < CPW; ++c) {
    const int ch = ch0 + c;
    float s = s_bd[ch];
    const float* wr = &s_wd[ch * R];
    #pragma unroll
    for (int j = 0; j < R; ++j) s = fmaf(xr[j], wr[j], s);
    dtb[(long)c * L] = softplus_f(s);
  }
}

// ---------------------------------------------------------------------------
// Selective scan (n=2 states), block-parallel affine scan over L.
// ---------------------------------------------------------------------------
__global__ __launch_bounds__(256) void scan_kernel(
    const float* __restrict__ dt_t, const float* __restrict__ xc_t,
    const float* __restrict__ z_t, const float* __restrict__ bc_t,
    const float* __restrict__ alog, const float* __restrict__ dd,
    float* __restrict__ y_t, int di, int L)
{
  const int ch = blockIdx.x;
  const int bz = blockIdx.y;
  const int tid = threadIdx.x;
  const int lane = tid & 63;
  const int w = tid >> 6;
  const long rowb = ((long)bz * di + ch) * L;
  const long bcb = (long)bz * 4 * L;
  const int l0 = tid * 16;

  __shared__ float wsP0[4], wsQ0[4], wsP1[4], wsQ1[4];

  const float A0 = -__expf(alog[ch * 2 + 0]);
  const float A1 = -__expf(alog[ch * 2 + 1]);
  const float ddc = dd[ch];

  float dtv[16], xcv[16], t0[16], t1[16];
  load16(dtv, dt_t + rowb + l0);
  load16(xcv, xc_t + rowb + l0);
  load16(t0, bc_t + bcb + l0);
  load16(t1, bc_t + bcb + L + l0);

  float a0[16], a1[16], u0[16], u1[16];
  float P0 = 1.0f, Q0 = 0.0f, P1 = 1.0f, Q1 = 0.0f;
  #pragma unroll
  for (int i = 0; i < 16; ++i) {
    const float dt = dtv[i];
    const float dx = dt * xcv[i];
    a0[i] = __expf(dt * A0);
    a1[i] = __expf(dt * A1);
    u0[i] = dx * t0[i];
    u1[i] = dx * t1[i];
    Q0 = fmaf(a0[i], Q0, u0[i]); P0 *= a0[i];
    Q1 = fmaf(a1[i], Q1, u1[i]); P1 *= a1[i];
  }

  #pragma unroll
  for (int off = 1; off < 64; off <<= 1) {
    const float pp0 = __shfl_up(P0, off);
    const float qq0 = __shfl_up(Q0, off);
    const float pp1 = __shfl_up(P1, off);
    const float qq1 = __shfl_up(Q1, off);
    if (lane >= off) {
      Q0 = fmaf(P0, qq0, Q0); P0 *= pp0;
      Q1 = fmaf(P1, qq1, Q1); P1 *= pp1;
    }
  }
  if (lane == 63) { wsP0[w] = P0; wsQ0[w] = Q0; wsP1[w] = P1; wsQ1[w] = Q1; }
  __syncthreads();
  float eQ0 = 0.0f, eQ1 = 0.0f;
  for (int ww = 0; ww < w; ++ww) {
    eQ0 = fmaf(wsP0[ww], eQ0, wsQ0[ww]);
    eQ1 = fmaf(wsP1[ww], eQ1, wsQ1[ww]);
  }
  float pP0 = __shfl_up(P0, 1), pQ0 = __shfl_up(Q0, 1);
  float pP1 = __shfl_up(P1, 1), pQ1 = __shfl_up(Q1, 1);
  if (lane == 0) { pP0 = 1.0f; pQ0 = 0.0f; pP1 = 1.0f; pQ1 = 0.0f; }
  float h0 = fmaf(pP0, eQ0, pQ0);
  float h1 = fmaf(pP1, eQ1, pQ1);

  float c0[16], c1[16], zv[16], yv[16];
  load16(c0, bc_t + bcb + 2 * L + l0);
  load16(c1, bc_t + bcb + 3 * L + l0);
  load16(zv, z_t + rowb + l0);
  #pragma unroll
  for (int i = 0; i < 16; ++i) {
    h0 = fmaf(a0[i], h0, u0[i]);
    h1 = fmaf(a1[i], h1, u1[i]);
    const float y = fmaf(h0, c0[i], fmaf(h1, c1[i], ddc * xcv[i]));
    yv[i] = y * silu_f(zv[i]);
  }
  store16(y_t + rowb + l0, yv);
}

// ---------------------------------------------------------------------------
extern "C" void kernel_launch(void* const* d_in, const int* in_sizes, int n_in,
                              void* d_out, int out_size, void* d_ws, size_t ws_size,
                              hipStream_t stream)
{
  const float* x       = (const float*)d_in[0];
  const float* lin_w   = (const float*)d_in[1];
  const float* lin_b   = (const float*)d_in[2];
  const float* s1_win  = (const float*)d_in[3];
  const float* s1_bin  = (const float*)d_in[4];
  const float* s1_cw   = (const float*)d_in[5];
  const float* s1_cb   = (const float*)d_in[6];
  const float* s1_wx   = (const float*)d_in[7];
  const float* s1_wdt  = (const float*)d_in[8];
  const float* s1_bdt  = (const float*)d_in[9];
  const float* s1_alog = (const float*)d_in[10];
  const float* s1_dd   = (const float*)d_in[11];
  const float* s1_wout = (const float*)d_in[12];
  const float* s1_lnw  = (const float*)d_in[13];
  const float* s1_lnb  = (const float*)d_in[14];
  const float* s2_win  = (const float*)d_in[15];
  const float* s2_bin  = (const float*)d_in[16];
  const float* s2_cw   = (const float*)d_in[17];
  const float* s2_cb   = (const float*)d_in[18];
  const float* s2_wx   = (const float*)d_in[19];
  const float* s2_wdt  = (const float*)d_in[20];
  const float* s2_bdt  = (const float*)d_in[21];
  const float* s2_alog = (const float*)d_in[22];
  const float* s2_dd   = (const float*)d_in[23];
  const float* s2_wout = (const float*)d_in[24];
  const float* s2_lnw  = (const float*)d_in[25];
  const float* s2_lnb  = (const float*)d_in[26];
  float* out = (float*)d_out;

  const int B = 8, L = 4096, M = 32768;
  const long SLOT = 8L * 256 * 4096;   // 8388608 elems = 32 MB
  const long HALF = SLOT / 2;          // 16 MB
  float* ws = (float*)d_ws;
  float* S0f = ws;             u32* S0u = (u32*)S0f;
  float* S1f = ws + SLOT;      u32* S1u = (u32*)S1f;
  float* S2f = ws + 2 * SLOT;  u32* S2u = (u32*)S2f;
  float* S3f = ws + 3 * SLOT;
  float* SBf = ws + 4 * SLOT;                       // (B,4,L) = 131072
  u32*   WP  = (u32*)(ws + 4 * SLOT + 131072);      // packed weights

  // 1. pack weights
  wprep_kernel<<<WTOT / 256, 256, 0, stream>>>(s1_win, s1_wout, lin_w, s2_win, s2_wout, WP);
  // 2. x (b,128,L) -> packed xT (M,128) @ S0u
  tpose_kernel<<<dim3(128, 4, B), 256, 0, stream>>>(x, S0u, 128, L);
  // 3. stage1 in-proj: -> xcpre1 @ S1f, z1 @ S1f+HALF
  mgemm_kernel<0><<<dim3(2, 256), 256, 0, stream>>>(
      S0u, WP + WOFF1, s1_bin, M, 256, 128, S1f, S1f + HALF, nullptr, 128, L);
  // 4. fused conv+xproj+dt: xc1 @ S2f, dt1 @ S2f+HALF, B/C @ SBf
  cxp_kernel<128, 8><<<dim3(64, B), 256, 0, stream>>>(
      S1f, s1_cw, s1_cb, s1_wx, s1_wdt, s1_bdt, S2f, S2f + HALF, SBf, L);
  // 5. scan1 -> y1 @ S0f
  scan_kernel<<<dim3(128, B), 256, 0, stream>>>(
      S2f + HALF, S2f, S1f + HALF, SBf, s1_alog, s1_dd, S0f, 128, L);
  // 6. y1 -> packed y1T @ S0u+HALF
  tpose_kernel<<<dim3(128, 4, B), 256, 0, stream>>>(S0f, S0u + HALF, 128, L);
  // 7. out-proj1 + LN -> act_mid packed @ S1u
  lgemm_kernel<128, 2><<<dim3(512), 256, 0, stream>>>(
      S0u + HALF, WP + WOFFO1, s1_lnw, s1_lnb, M, 128, S1u, nullptr, L);
  // 8. mid linear + silu -> act_lin packed @ S2u
  mgemm_kernel<1><<<dim3(2, 256), 256, 0, stream>>>(
      S1u, WP + WOFFL, lin_b, M, 256, 128, nullptr, nullptr, S2u, 0, L);
  // 9. stage2 in-proj: -> xcpre2 @ S0f, z2 @ S1f
  mgemm_kernel<0><<<dim3(4, 256), 256, 0, stream>>>(
      S2u, WP + WOFF2, s2_bin, M, 512, 256, S0f, S1f, nullptr, 256, L);
  // 10. fused conv+xproj+dt: xc2 @ S3f, dt2 @ S2f, B/C @ SBf
  cxp_kernel<256, 16><<<dim3(64, B), 256, 0, stream>>>(
      S0f, s2_cw, s2_cb, s2_wx, s2_wdt, s2_bdt, S3f, S2f, SBf, L);
  // 11. scan2 -> y2 @ S0f
  scan_kernel<<<dim3(256, B), 256, 0, stream>>>(
      S2f, S3f, S1f, SBf, s2_alog, s2_dd, S0f, 256, L);
  // 12. y2 -> packed y2T @ S1u
  tpose_kernel<<<dim3(128, 8, B), 256, 0, stream>>>(S0f, S1u, 256, L);
  // 13. out-proj2 + LN -> d_out fp32 (b,256,64,64)
  lgemm_kernel<256, 3><<<dim3(512), 256, 0, stream>>>(
      S1u, WP + WOFFO2, s2_lnw, s2_lnb, M, 256, nullptr, out, L);
}